// Round 9
// baseline (163.116 us; speedup 1.0000x reference)
//
#include <hip/hip_runtime.h>
#include <math.h>

// Problem constants (match reference).
#define BDIM 4096
#define TDIM 2048
#define NBLK 512          // k1 grid: BDIM / RPB  (partial stays [512][2048] = 4 MB)
#define RPB  8            // rows per k1 block

// gamma powers as exact compile-time folded constants
constexpr double gpow(int e) {
    double r = 1.0;
    for (int i = 0; i < e; ++i) r *= 0.99;
    return r;
}

__device__ __forceinline__ float logsig_fast(float x) {
    // log(sigmoid(x)) = min(x,0) - log(1 + exp(-|x|)); HW transcendentals.
    float z = __expf(-fabsf(x));
    return fminf(x, 0.0f) - __logf(1.0f + z);
}

__device__ __forceinline__ float clip5(float x) {
    return fminf(fmaxf(x, -5.0f), 5.0f);
}

// ---------------------------------------------------------------------------
// K1: per-row reverse discounted scan (c[t] = wr[t] + g*c[t+1]); writes cum
// and per-block column partials.
// 1024 THREADS/BLOCK (2 cols/thread, 16 waves) -> 32 waves/CU at 2 blocks/CU
// — the occupancy where the harness fill kernels hit 82% of HBM peak.
// One barrier per row; 16-wave carry chain is 15 static FMAs + select.
// Blocks 0/1 zero colsum/obj (replaces memsets).
// ---------------------------------------------------------------------------
__global__ __launch_bounds__(1024, 8) void k1_scan(
    const float* __restrict__ logits,
    const float* __restrict__ weight,
    const float* __restrict__ baselines,
    float* __restrict__ cum_out,
    float* __restrict__ partial,
    float* __restrict__ colsum,
    float* __restrict__ obj)
{
    const int tid  = threadIdx.x;     // 0..1023
    const int lane = tid & 63;
    const int wave = tid >> 6;        // 0..15
    const int t0   = tid * 2;         // 2 contiguous columns per thread

    // in-kernel zeroing (k2/k3/k4 are stream-ordered after k1)
    if (blockIdx.x == 0) {
        *reinterpret_cast<float2*>(colsum + t0) = make_float2(0.f, 0.f);
    }
    if (blockIdx.x == 1) {
        *reinterpret_cast<float2*>(obj + t0) = make_float2(0.f, 0.f);
    }

    const float G    = 0.99f;
    const float G128 = (float)gpow(128);       // one wave spans 64*2 = 128 cols
    const float LOG2G = -0.014499569695115089f;  // log2(0.99)
    // gamma^(2-k) for k=0..1
    const float gk[2] = {(float)gpow(2), (float)gpow(1)};
    // shuffle-scan factors gamma^(2*2^s), s=0..5
    const float fs[6] = {(float)gpow(2),  (float)gpow(4),  (float)gpow(8),
                         (float)gpow(16), (float)gpow(32), (float)gpow(64)};
    // gamma^((64-lane)*2): distance from this thread's first col to wave-region end
    const float lane_pow = exp2f((float)((64 - lane) * 2) * LOG2G);

    __shared__ float wsum[2][16];   // [iter parity][wave]

    float colacc[2];
    colacc[0] = 0.0f; colacc[1] = 0.0f;

    const int row0 = blockIdx.x * RPB;
    size_t base = (size_t)row0 * TDIM + t0;

    // preload row 0
    float2 x0 = *reinterpret_cast<const float2*>(logits + base);
    float2 w0 = *reinterpret_cast<const float2*>(weight + base);
    float2 b0 = *reinterpret_cast<const float2*>(baselines + base);

    for (int r = 0; r < RPB; ++r) {
        const size_t nbase = base + TDIM;
        const bool has_next = (r + 1 < RPB);

        float wr[2];
        wr[0] = w0.x * logsig_fast(x0.x);
        wr[1] = w0.y * logsig_fast(x0.y);

        // prefetch next row: latency hides under the scan chain below
        float2 nx0, nw0, nb0;
        if (has_next) {
            nx0 = *reinterpret_cast<const float2*>(logits + nbase);
            nw0 = *reinterpret_cast<const float2*>(weight + nbase);
            nb0 = *reinterpret_cast<const float2*>(baselines + nbase);
        }

        // local suffix scan over 2 elems
        float loc[2];
        loc[1] = wr[1];
        loc[0] = fmaf(G, wr[1], wr[0]);

        // wave-level weighted suffix scan over per-thread totals
        float v = loc[0];
#pragma unroll
        for (int s = 0; s < 6; ++s) {
            const int o = 1 << s;
            float up = __shfl_down(v, (unsigned)o, 64);
            if (lane + o < 64) v = fmaf(fs[s], up, v);
        }

        // cross-wave carry via LDS over 16 waves — ONE barrier per row
        const int buf = r & 1;
        if (lane == 0) wsum[buf][wave] = v;
        __syncthreads();
        // C_w = suffix carry entering wave w's region (static chain + select)
        const float W1  = wsum[buf][1],  W2  = wsum[buf][2],  W3  = wsum[buf][3];
        const float W4  = wsum[buf][4],  W5  = wsum[buf][5],  W6  = wsum[buf][6];
        const float W7  = wsum[buf][7],  W8  = wsum[buf][8],  W9  = wsum[buf][9];
        const float W10 = wsum[buf][10], W11 = wsum[buf][11], W12 = wsum[buf][12];
        const float W13 = wsum[buf][13], W14 = wsum[buf][14], W15 = wsum[buf][15];
        const float C14 = W15;
        const float C13 = fmaf(G128, C14, W14);
        const float C12 = fmaf(G128, C13, W13);
        const float C11 = fmaf(G128, C12, W12);
        const float C10 = fmaf(G128, C11, W11);
        const float C9  = fmaf(G128, C10, W10);
        const float C8  = fmaf(G128, C9,  W9);
        const float C7  = fmaf(G128, C8,  W8);
        const float C6  = fmaf(G128, C7,  W7);
        const float C5  = fmaf(G128, C6,  W6);
        const float C4  = fmaf(G128, C5,  W5);
        const float C3  = fmaf(G128, C4,  W4);
        const float C2  = fmaf(G128, C3,  W3);
        const float C1  = fmaf(G128, C2,  W2);
        const float C0  = fmaf(G128, C1,  W1);
        const float carry =
            (wave == 0)  ? C0  : (wave == 1)  ? C1  : (wave == 2)  ? C2  :
            (wave == 3)  ? C3  : (wave == 4)  ? C4  : (wave == 5)  ? C5  :
            (wave == 6)  ? C6  : (wave == 7)  ? C7  : (wave == 8)  ? C8  :
            (wave == 9)  ? C9  : (wave == 10) ? C10 : (wave == 11) ? C11 :
            (wave == 12) ? C12 : (wave == 13) ? C13 : (wave == 14) ? C14 : 0.0f;

        // full suffix value at this thread's first element
        const float vfull = fmaf(lane_pow, carry, v);
        // cumulative at element t0+2 (tail): next lane's vfull; lane 63 -> carry
        const float vn = __shfl_down(vfull, 1, 64);
        const float tail = (lane == 63) ? carry : vn;

        float c[2];
        c[0] = fmaf(gk[0], tail, loc[0]);
        c[1] = fmaf(gk[1], tail, loc[1]);

        *reinterpret_cast<float2*>(cum_out + base) = make_float2(c[0], c[1]);

        colacc[0] += c[0] - b0.x;
        colacc[1] += c[1] - b0.y;

        base = nbase;
        if (has_next) {
            x0 = nx0; w0 = nw0; b0 = nb0;
        }
    }

    const size_t pbase = (size_t)blockIdx.x * TDIM + t0;
    *reinterpret_cast<float2*>(partial + pbase) = make_float2(colacc[0], colacc[1]);
}

// ---------------------------------------------------------------------------
// K2: colsum[col] = sum over 512 partial rows (32 slices x 16 rows).
// ---------------------------------------------------------------------------
__global__ __launch_bounds__(256) void k2_colsum(
    const float* __restrict__ partial, float* __restrict__ colsum)
{
    const int gid = blockIdx.x * 256 + threadIdx.x;   // 0..65535
    const int col = gid & (TDIM - 1);
    const int slc = gid >> 11;                        // 0..31
    const float* p = partial + (size_t)slc * 16 * TDIM + col;
    float s = 0.0f;
#pragma unroll
    for (int i = 0; i < 16; ++i) s += p[(size_t)i * TDIM];
    atomicAdd(colsum + col, s);
}

// ---------------------------------------------------------------------------
// K3: per-y-block objective partials — NO atomics.
// grid (4, 512) = 2048 blocks = 32 waves/CU; 8 rows/thread, float2 cols.
// ---------------------------------------------------------------------------
#define K3_ROWS 8
__global__ __launch_bounds__(256) void k3_part(
    const float* __restrict__ cum,
    const float* __restrict__ baselines,
    const float* __restrict__ lp,
    const float* __restrict__ colsum,
    float* __restrict__ objpart)
{
    const int c2 = (blockIdx.x * 256 + threadIdx.x) * 2;   // column pair
    const int yb = blockIdx.y;                             // 0..511
    const int r0 = yb * K3_ROWS;
    const float inv = 1.0f / (float)BDIM;
    float2 ms = *reinterpret_cast<const float2*>(colsum + c2);
    const float m0 = ms.x * inv, m1 = ms.y * inv;

    float a0 = 0.0f, a1 = 0.0f;
    size_t idx = (size_t)r0 * TDIM + c2;
#pragma unroll
    for (int r = 0; r < K3_ROWS; ++r, idx += TDIM) {
        float2 c = *reinterpret_cast<const float2*>(cum + idx);
        float2 b = *reinterpret_cast<const float2*>(baselines + idx);
        float2 l = *reinterpret_cast<const float2*>(lp + idx);
        a0 = fmaf(clip5(c.x - b.x - m0), l.x, a0);
        a1 = fmaf(clip5(c.y - b.y - m1), l.y, a1);
    }
    *reinterpret_cast<float2*>(objpart + (size_t)yb * TDIM + c2) = make_float2(a0, a1);
}

// ---------------------------------------------------------------------------
// K4: obj[col] = sum over 512 objpart rows (32 slices x 16 rows) — k2 clone.
// ---------------------------------------------------------------------------
__global__ __launch_bounds__(256) void k4_objsum(
    const float* __restrict__ objpart, float* __restrict__ obj)
{
    const int gid = blockIdx.x * 256 + threadIdx.x;   // 0..65535
    const int col = gid & (TDIM - 1);
    const int slc = gid >> 11;                        // 0..31
    const float* p = objpart + (size_t)slc * 16 * TDIM + col;
    float s = 0.0f;
#pragma unroll
    for (int i = 0; i < 16; ++i) s += p[(size_t)i * TDIM];
    atomicAdd(obj + col, s);
}

extern "C" void kernel_launch(void* const* d_in, const int* in_sizes, int n_in,
                              void* d_out, int out_size, void* d_ws, size_t ws_size,
                              hipStream_t stream) {
    const float* log_probs = (const float*)d_in[0];   // [B,T]
    const float* logits    = (const float*)d_in[1];   // [B,T,1]
    const float* weight    = (const float*)d_in[2];   // [B,T]
    const float* baselines = (const float*)d_in[3];   // [B,T,1]

    float* out = (float*)d_out;
    float* obj = out;            // [T]
    float* cum = out + TDIM;     // [B,T]

    float* partial = (float*)d_ws;                       // [512][2048] = 4 MB
    float* colsum  = partial + (size_t)NBLK * TDIM;      // 2048 floats

    // k1 writes partial (colacc) and zeroes colsum/obj.
    k1_scan<<<NBLK, 1024, 0, stream>>>(logits, weight, baselines, cum, partial, colsum, obj);
    // k2 consumes partial -> colsum.
    k2_colsum<<<256, 256, 0, stream>>>(partial, colsum);
    // k3 reuses partial as objpart (k2 finished reading it; stream-ordered).
    k3_part<<<dim3(4, 512), 256, 0, stream>>>(cum, baselines, log_probs, colsum, partial);
    // k4 reduces objpart -> obj.
    k4_objsum<<<256, 256, 0, stream>>>(partial, obj);
}